// Round 7
// baseline (80.504 us; speedup 1.0000x reference)
//
#include <hip/hip_runtime.h>

// Problem constants (N=1, D=64, NCLS=21, R=C=512, R_IN=C_IN=256)
#define M_TOT 65536   // R_IN*C_IN
#define LBS_S 262144  // R*C
#define NBINS 1024    // 32x32 bins of 16x16 rp-sites

typedef _Float16 h2 __attribute__((ext_vector_type(2)));
typedef _Float16 h8 __attribute__((ext_vector_type(8)));
union H8 { h8 v; h2 h[4]; };

__device__ __forceinline__ int rfl(int v) { return __builtin_amdgcn_readfirstlane(v); }
__device__ __forceinline__ float bperm(int l, float v) {
  return __int_as_float(__builtin_amdgcn_ds_bpermute(l << 2, __float_as_int(v)));
}
__device__ __forceinline__ int bpermi(int l, int v) {
  return __builtin_amdgcn_ds_bpermute(l << 2, v);
}
// Multiplexed butterfly merge: lanes with `hi` keep reducing b, others a.
__device__ __forceinline__ float merge2(float a, float b, bool hi, int xo) {
  const float keep = hi ? b : a;
  const float send = hi ? a : b;
  return keep + __shfl_xor(send, xo, 64);
}

#if __has_builtin(__builtin_amdgcn_fdot2)
__device__ __forceinline__ float fdot2(h2 a, h2 b, float c) {
  return __builtin_amdgcn_fdot2(a, b, c, false);
}
#else
__device__ __forceinline__ float fdot2(h2 a, h2 b, float c) {
  return fmaf((float)a.x, (float)b.x, fmaf((float)a.y, (float)b.y, c));
}
#endif

// ---------------------------------------------------------------------------
// Fused prep: blocks 0-1023 transpose feat (64,65536)f32 -> (65536,64)fp16;
// blocks 1024-2047 transpose lbs (21,262144)f32 -> (262144,21)fp16.
// Block 0 zeroes the 1024-bin histogram (used by k_n2's hist duty next).
// ---------------------------------------------------------------------------
__global__ __launch_bounds__(256) void k_prep(const float* __restrict__ feat,
                                              const float* __restrict__ lbs,
                                              _Float16* __restrict__ feat_h,
                                              _Float16* __restrict__ lbs_h,
                                              int* __restrict__ hist) {
  __shared__ float ldsf[64 * 65];
  const int l = threadIdx.x & 63;
  const int w = threadIdx.x >> 6;
  if (blockIdx.x == 0) {
#pragma unroll
    for (int k = 0; k < 4; ++k) hist[k * 256 + threadIdx.x] = 0;
  }
  if (blockIdx.x < 1024) {
    float(*tile)[65] = (float(*)[65])ldsf;
    const int s0 = blockIdx.x * 64;
#pragma unroll
    for (int k = 0; k < 16; ++k) {
      const int d = w * 16 + k;
      tile[d][l] = feat[(size_t)d * M_TOT + s0 + l];
    }
    __syncthreads();
    const int lh = l & 31, hs = l >> 5;
    h2* out2 = (h2*)feat_h;
#pragma unroll
    for (int k = 0; k < 8; ++k) {
      const int s = w * 16 + 2 * k + hs;
      h2 v;
      v.x = (_Float16)tile[2 * lh][s];
      v.y = (_Float16)tile[2 * lh + 1][s];
      out2[(size_t)(s0 + s) * 32 + lh] = v;  // 256B coalesced
    }
  } else {
    _Float16* buf = ((_Float16*)ldsf) + w * (64 * 21);
    const int sb = (blockIdx.x - 1024) * 256 + w * 64;
#pragma unroll
    for (int c = 0; c < 21; ++c)
      buf[l * 21 + c] = (_Float16)lbs[(size_t)c * LBS_S + sb + l];
    __syncthreads();
    const uint32_t* src = (const uint32_t*)buf;
    uint32_t* dst = (uint32_t*)(lbs_h + (size_t)sb * 21);  // sb*42 B, dword-aligned
#pragma unroll
    for (int k = 0; k < 11; ++k) {
      const int i = k * 64 + l;
      if (i < 672) dst[i] = src[i];  // 672 dwords = 64 sites * 42 B
    }
  }
}

__device__ __forceinline__ int pixel_key(const float* grid_inte, const float* grid, int i) {
  const float dx = grid[(2 * 512 + 2) * 2 + 0] - grid[(1 * 512 + 2) * 2 + 0];
  const float dy = grid[(2 * 512 + 2) * 2 + 1] - grid[(2 * 512 + 1) * 2 + 1];
  const int rp0 = (int)floorf(grid_inte[i * 2 + 0] / dx);
  const int rp1 = (int)floorf(grid_inte[i * 2 + 1] / dy);
  return ((rp0 >> 4) << 5) | (rp1 >> 4);  // 32x32 bins
}

// ---------------------------------------------------------------------------
// N2[site] = ||feat_grid[:, site]||^2, quad-major: n2[(a*256+b)*4 + ey*2+ex].
// 8 quads per wave. Blocks 0-255 additionally histogram the pixels (hist was
// zeroed by k_prep, which completes before this kernel starts).
// ---------------------------------------------------------------------------
__global__ __launch_bounds__(256) void k_n2(const _Float16* __restrict__ feat_h,
                                            float* __restrict__ n2,
                                            const float* __restrict__ grid_inte,
                                            const float* __restrict__ grid,
                                            int* __restrict__ hist) {
  if (blockIdx.x < 256) {
    const int i = blockIdx.x * 256 + threadIdx.x;
    atomicAdd(&hist[pixel_key(grid_inte, grid, i)], 1);
  }
  const int lane = threadIdx.x & 63;
  const int cb = lane & 7;
  const int g = lane >> 3;
  const int quad = blockIdx.x * 32 + (int)(threadIdx.x >> 6) * 8 + g;
  const int a = quad >> 8;
  const int b = quad & 255;
  const int ra[3] = {max(a - 1, 0), a, min(a + 1, 255)};
  const int cbn[3] = {max(b - 1, 0), b, min(b + 1, 255)};

  const h8* fp = (const h8*)feat_h;
  H8 F[3][3];
#pragma unroll
  for (int i = 0; i < 3; ++i)
#pragma unroll
    for (int j = 0; j < 3; ++j)
      F[i][j].v = fp[(size_t)((ra[i] << 8) + cbn[j]) * 8 + cb];

  h2 wyh[2], wxh[2];
  int cye[2], cxe[2];
#pragma unroll
  for (int e = 0; e < 2; ++e) {
    const float yf = fminf(fmaxf((float)(2 * a + e) * 0.5f - 0.25f, 0.0f), 255.0f);
    const int y0 = min((int)yf, 254);
    wyh[e].x = wyh[e].y = (_Float16)(yf - (float)y0);
    cye[e] = y0 - (a - 1);
    const float xf = fminf(fmaxf((float)(2 * b + e) * 0.5f - 0.25f, 0.0f), 255.0f);
    const int x0 = min((int)xf, 254);
    wxh[e].x = wxh[e].y = (_Float16)(xf - (float)x0);
    cxe[e] = x0 - (b - 1);
  }

  H8 colv[3][2];
#pragma unroll
  for (int r = 0; r < 3; ++r)
#pragma unroll
    for (int e = 0; e < 2; ++e) {
      const bool s1 = (cxe[e] == 1);
#pragma unroll
      for (int q = 0; q < 4; ++q) {
        const h2 A = s1 ? F[r][1].h[q] : F[r][0].h[q];
        const h2 B = s1 ? F[r][2].h[q] : F[r][1].h[q];
        colv[r][e].h[q] = A + wxh[e] * (B - A);
      }
    }

  float sq[4];
#pragma unroll
  for (int ey = 0; ey < 2; ++ey)
#pragma unroll
    for (int ex = 0; ex < 2; ++ex) {
      const bool s1 = (cye[ey] == 1);
      float nn = 0.0f;
#pragma unroll
      for (int q = 0; q < 4; ++q) {
        const h2 A = s1 ? colv[1][ex].h[q] : colv[0][ex].h[q];
        const h2 B = s1 ? colv[2][ex].h[q] : colv[1][ex].h[q];
        const h2 v = A + wyh[ey] * (B - A);
        nn = fdot2(v, v, nn);
      }
      sq[ey * 2 + ex] = nn;
    }

  const bool b0 = lane & 1, b1 = lane & 2;
  float m0 = merge2(sq[0], sq[1], b0, 1);
  float m1 = merge2(sq[2], sq[3], b0, 1);
  float mm = merge2(m0, m1, b1, 2);
  mm += __shfl_xor(mm, 4, 64);
  if ((lane & 7) < 4) n2[quad * 4 + (lane & 3)] = mm;
}

// Exclusive scan of 1024 bins -> cursor (single block, 256 threads).
__global__ __launch_bounds__(256) void k_scan(const int* __restrict__ hist,
                                              int* __restrict__ cursor) {
  __shared__ int wsum[4];
  const int t = threadIdx.x;
  const int4 h = ((const int4*)hist)[t];
  const int s = h.x + h.y + h.z + h.w;
  int sc = s;  // inclusive scan within the 64-lane wave
#pragma unroll
  for (int o = 1; o < 64; o <<= 1) {
    const int u = __shfl_up(sc, o, 64);
    if ((t & 63) >= o) sc += u;
  }
  if ((t & 63) == 63) wsum[t >> 6] = sc;
  __syncthreads();
  int base = 0;
  for (int wv = 0; wv < (t >> 6); ++wv) base += wsum[wv];
  const int ex = base + sc - s;
  cursor[4 * t + 0] = ex;
  cursor[4 * t + 1] = ex + h.x;
  cursor[4 * t + 2] = ex + h.x + h.y;
  cursor[4 * t + 3] = ex + h.x + h.y + h.z;
}

__global__ __launch_bounds__(256) void k_scatter(const float* __restrict__ grid_inte,
                                                 const float* __restrict__ grid,
                                                 int* __restrict__ cursor,
                                                 int* __restrict__ order,
                                                 int* __restrict__ inv) {
  const int i = blockIdx.x * 256 + threadIdx.x;
  const int pos = atomicAdd(&cursor[pixel_key(grid_inte, grid, i)], 1);
  order[pos] = i;
  inv[i] = pos;
}

// ---------------------------------------------------------------------------
// Main kernel. One wave per pixel (bin-sorted order). Writes its result to
// tmp[p*21+c] at its SORTED position p (contiguous, coalesced) — the unsort
// kernel produces the final layout. Dot/tap/vote stages as in round 4.
// ---------------------------------------------------------------------------
__global__ __launch_bounds__(256) void k_main(const float* __restrict__ grid_inte,
                                              const float* __restrict__ grid,
                                              const _Float16* __restrict__ feat_h,
                                              const _Float16* __restrict__ lbs_h,
                                              const float* __restrict__ n2,
                                              const float* __restrict__ wei_p,
                                              const int* __restrict__ order,
                                              float* __restrict__ tmp) {
  const int lane = threadIdx.x & 63;
  const int bid = (int)blockIdx.x;
  // XCD-chunked swizzle: consecutive sorted blocks -> same XCD (16384 = 8*2048)
  const int bswz = ((bid & 7) << 11) | (bid >> 3);
  const int p = bswz * 4 + (int)(threadIdx.x >> 6);  // sorted position
  const int m = rfl(order[p]);

  const float dx = grid[(2 * 512 + 2) * 2 + 0] - grid[(1 * 512 + 2) * 2 + 0];
  const float dy = grid[(2 * 512 + 2) * 2 + 1] - grid[(2 * 512 + 1) * 2 + 1];
  const float wei = wei_p[0];

  const float gi0 = grid_inte[m * 2 + 0];
  const float gi1 = grid_inte[m * 2 + 1];
  const int rp0 = rfl((int)floorf(gi0 / dx));
  const int rp1 = rfl((int)floorf(gi1 / dy));
  const int by = (rp0 - 3) >> 1;  // 4x4 patch base (scalar)
  const int bx = (rp1 - 3) >> 1;

  const int cb = lane & 7;
  const int g = lane >> 3;
  const h8* fp = (const h8*)feat_h;

  // ---- Issue feat loads (center + 2 patch) ----
  H8 C, P0, P1;
  C.v = fp[(size_t)m * 8 + cb];
  {
    const int s0 = g;
    const int yy0 = min(max(by + (s0 >> 2), 0), 255);
    const int xx0 = min(max(bx + (s0 & 3), 0), 255);
    P0.v = fp[(size_t)((yy0 << 8) + xx0) * 8 + cb];
    const int s1 = 8 + g;
    const int yy1 = min(max(by + (s1 >> 2), 0), 255);
    const int xx1 = min(max(bx + (s1 & 3), 0), 255);
    P1.v = fp[(size_t)((yy1 << 8) + xx1) * 8 + cb];
  }

  // ---- Tap geometry (VALU only, independent of feat loads) ----
  const int t = lane;
  const int ti = (t * 13) >> 6;  // t/5 for t < 25
  const int tj = t - 5 * ti;
  const int r5 = min(max(rp0 + ti - 2, 0), 511);
  const int c5 = min(max(rp1 + tj - 2, 0), 511);
  const float yf = fminf(fmaxf((float)r5 * 0.5f - 0.25f, 0.0f), 255.0f);
  const int y0 = min((int)yf, 254);
  const float wy = yf - (float)y0;
  const int qy = y0 - by;  // in [0,2] for t<25
  const float xf = fminf(fmaxf((float)c5 * 0.5f - 0.25f, 0.0f), 255.0f);
  const int x0 = min((int)xf, 254);
  const float wx = xf - (float)x0;
  const int qx = x0 - bx;
  const int lidx = r5 * 512 + c5;

  // ---- Issue n2 gather ----
  const float n2g = n2[(((r5 >> 1) << 8) + (c5 >> 1)) * 4 + ((r5 & 1) * 2 + (c5 & 1))];

  // ---- Prefetch the 9 lbs vote gathers (depend only on rp, not on dist) ----
  const int vg = (lane >= 42) ? 2 : ((lane >= 21) ? 1 : 0);
  const int cc = min(lane - 21 * vg, 20);
  float lg[9];
#pragma unroll
  for (int it = 0; it < 9; ++it) {
    const int tt = 3 * it + vg;          // taps 25,26 masked later via dist==0
    const int idxt = bpermi(tt, lidx);   // clamped coords -> in-bounds
    lg[it] = (float)lbs_h[idxt * 21 + cc];
  }

  // ---- Dot stage (consumes patch loads) ----
  float nhp = 0.0f;
#pragma unroll
  for (int q = 0; q < 4; ++q) nhp = fdot2(C.h[q], C.h[q], nhp);
  nhp *= -0.5f;
  float pa = nhp, pb = nhp;
#pragma unroll
  for (int q = 0; q < 4; ++q) {
    pa = fdot2(P0.h[q], C.h[q], pa);
    pb = fdot2(P1.h[q], C.h[q], pb);
  }
  float Dv = merge2(pa, pb, lane & 1, 1);
  Dv += __shfl_xor(Dv, 2, 64);
  Dv += __shfl_xor(Dv, 4, 64);
  // lane L holds D'_s, s = 8*(L&1) + (L>>3); source lane for s: ((s&7)<<3)|(s>>3)

  // ---- Bilinear in D' space, mse, dist ----
  const int s00 = qy * 4 + qx;
  const int s01 = s00 + 1, s10 = s00 + 4, s11 = s00 + 5;
  const int l00 = ((s00 & 7) << 3) | (s00 >> 3);
  const int l01 = ((s01 & 7) << 3) | (s01 >> 3);
  const int l10 = ((s10 & 7) << 3) | (s10 >> 3);
  const int l11 = ((s11 & 7) << 3) | (s11 >> 3);
  const float d00 = bperm(l00, Dv);
  const float d01 = bperm(l01, Dv);
  const float d10 = bperm(l10, Dv);
  const float d11 = bperm(l11, Dv);
  const float lo = fmaf(wx, d01 - d00, d00);
  const float hi = fmaf(wx, d11 - d10, d10);
  const float crossD = fmaf(wy, hi - lo, lo);

  const float mse = fmaf(-2.0f, crossD, n2g) * 0.015625f;  // /64
  float dist = __expf(-wei * mse);
  dist = (t < 25) ? dist : 0.0f;

  float den = dist;
#pragma unroll
  for (int o = 1; o < 64; o <<= 1) den += __shfl_xor(den, o, 64);

  // ---- Vote: fma with prefetched lg ----
  float vote = 0.0f;
#pragma unroll
  for (int it = 0; it < 9; ++it) {
    const float dt = bperm(3 * it + vg, dist);
    vote = fmaf(lg[it], dt, vote);
  }
  const float va = bperm(lane + 21, vote);
  const float vb = bperm(lane + 42, vote);
  const float vtot = vote + va + vb;

  // Coalesced write at the SORTED position (336 contiguous B per block).
  if (lane < 21) tmp[(size_t)p * 21 + lane] = vtot / fmaxf(den, 1e-15f);
}

// ---------------------------------------------------------------------------
// Unsort: thread per output pixel m; gather 84B from tmp (L2/L3-resident),
// write out[c*M+m] fully coalesced (21 x 1KB rows per block).
// ---------------------------------------------------------------------------
__global__ __launch_bounds__(256) void k_unsort(const float* __restrict__ tmp,
                                                const int* __restrict__ inv,
                                                float* __restrict__ out) {
  const int m = blockIdx.x * 256 + threadIdx.x;
  const int p = inv[m];
  const float* src = tmp + (size_t)p * 21;
  float v[21];
#pragma unroll
  for (int c = 0; c < 21; ++c) v[c] = src[c];
#pragma unroll
  for (int c = 0; c < 21; ++c) out[(size_t)c * M_TOT + m] = v[c];
}

extern "C" void kernel_launch(void* const* d_in, const int* in_sizes, int n_in,
                              void* d_out, int out_size, void* d_ws, size_t ws_size,
                              hipStream_t stream) {
  const float* grid_inte = (const float*)d_in[0];  // (1,256,256,2)
  const float* grid      = (const float*)d_in[1];  // (1,512,512,2)
  const float* feat      = (const float*)d_in[2];  // (1,64,256,256)
  const float* lbs       = (const float*)d_in[3];  // (1,21,512,512)
  const float* wei       = (const float*)d_in[4];  // scalar
  float* out = (float*)d_out;                      // (1,21,256,256)

  char* ws = (char*)d_ws;
  _Float16* feat_h = (_Float16*)ws;                         // 8,388,608 B
  _Float16* lbs_h  = (_Float16*)(ws + 8388608);             // 11,010,048 B
  float*    n2v    = (float*)(ws + 19398656);               // 1,048,576 B
  int*      order  = (int*)(ws + 20447232);                 // 262,144 B
  int*      inv    = (int*)(ws + 20709376);                 // 262,144 B
  int*      hist   = (int*)(ws + 20971520);                 // 4,096 B
  int*      cursor = (int*)(ws + 20975616);                 // 4,096 B
  float*    tmp    = (float*)(ws + 20979712);               // 5,505,024 B

  hipLaunchKernelGGL(k_prep, dim3(2048), dim3(256), 0, stream, feat, lbs, feat_h, lbs_h, hist);
  hipLaunchKernelGGL(k_n2, dim3(M_TOT / 32), dim3(256), 0, stream, feat_h, n2v, grid_inte, grid, hist);
  hipLaunchKernelGGL(k_scan, dim3(1), dim3(256), 0, stream, hist, cursor);
  hipLaunchKernelGGL(k_scatter, dim3(M_TOT / 256), dim3(256), 0, stream, grid_inte, grid, cursor, order, inv);
  hipLaunchKernelGGL(k_main, dim3(M_TOT / 4), dim3(256), 0, stream,
                     grid_inte, grid, feat_h, lbs_h, n2v, wei, order, tmp);
  hipLaunchKernelGGL(k_unsort, dim3(M_TOT / 256), dim3(256), 0, stream, tmp, inv, out);
}

// Round 8
// 58.920 us; speedup vs baseline: 1.3663x; 1.3663x over previous
//
#include <hip/hip_runtime.h>

// Problem constants (N=1, D=64, NCLS=21, R=C=512, R_IN=C_IN=256)
#define M_TOT 65536   // R_IN*C_IN
#define LBS_S 262144  // R*C

typedef _Float16 h2 __attribute__((ext_vector_type(2)));
typedef _Float16 h8 __attribute__((ext_vector_type(8)));
union H8 { h8 v; h2 h[4]; };

__device__ __forceinline__ int rfl(int v) { return __builtin_amdgcn_readfirstlane(v); }
__device__ __forceinline__ float bperm(int l, float v) {
  return __int_as_float(__builtin_amdgcn_ds_bpermute(l << 2, __float_as_int(v)));
}
__device__ __forceinline__ int bpermi(int l, int v) {
  return __builtin_amdgcn_ds_bpermute(l << 2, v);
}
// Multiplexed butterfly merge: lanes with `hi` keep reducing b, others a.
__device__ __forceinline__ float merge2(float a, float b, bool hi, int xo) {
  const float keep = hi ? b : a;
  const float send = hi ? a : b;
  return keep + __shfl_xor(send, xo, 64);
}

#if __has_builtin(__builtin_amdgcn_fdot2)
__device__ __forceinline__ float fdot2(h2 a, h2 b, float c) {
  return __builtin_amdgcn_fdot2(a, b, c, false);
}
#else
__device__ __forceinline__ float fdot2(h2 a, h2 b, float c) {
  return fmaf((float)a.x, (float)b.x, fmaf((float)a.y, (float)b.y, c));
}
#endif

// ---------------------------------------------------------------------------
// Fused prep: blocks 0-1023 transpose feat (64,65536)f32 -> (65536,64)fp16;
// blocks 1024-2047 transpose lbs (21,262144)f32 -> (262144,21)fp16.
// ---------------------------------------------------------------------------
__global__ __launch_bounds__(256) void k_prep(const float* __restrict__ feat,
                                              const float* __restrict__ lbs,
                                              _Float16* __restrict__ feat_h,
                                              _Float16* __restrict__ lbs_h) {
  __shared__ float ldsf[64 * 65];
  const int l = threadIdx.x & 63;
  const int w = threadIdx.x >> 6;
  if (blockIdx.x < 1024) {
    float(*tile)[65] = (float(*)[65])ldsf;
    const int s0 = blockIdx.x * 64;
#pragma unroll
    for (int k = 0; k < 16; ++k) {
      const int d = w * 16 + k;
      tile[d][l] = feat[(size_t)d * M_TOT + s0 + l];
    }
    __syncthreads();
    const int lh = l & 31, hs = l >> 5;
    h2* out2 = (h2*)feat_h;
#pragma unroll
    for (int k = 0; k < 8; ++k) {
      const int s = w * 16 + 2 * k + hs;
      h2 v;
      v.x = (_Float16)tile[2 * lh][s];
      v.y = (_Float16)tile[2 * lh + 1][s];
      out2[(size_t)(s0 + s) * 32 + lh] = v;  // 256B coalesced
    }
  } else {
    _Float16* buf = ((_Float16*)ldsf) + w * (64 * 21);
    const int sb = (blockIdx.x - 1024) * 256 + w * 64;
#pragma unroll
    for (int c = 0; c < 21; ++c)
      buf[l * 21 + c] = (_Float16)lbs[(size_t)c * LBS_S + sb + l];
    __syncthreads();
    const uint32_t* src = (const uint32_t*)buf;
    uint32_t* dst = (uint32_t*)(lbs_h + (size_t)sb * 21);  // sb*42 B, dword-aligned
#pragma unroll
    for (int k = 0; k < 11; ++k) {
      const int i = k * 64 + l;
      if (i < 672) dst[i] = src[i];  // 672 dwords = 64 sites * 42 B
    }
  }
}

// ---------------------------------------------------------------------------
// N2[site] = ||feat_grid[:, site]||^2, SITE-MAJOR: n2[r*512 + c].
// 8 quads per wave: lane = (group g = L>>3 -> quad, channel-block cb = L&7).
// ---------------------------------------------------------------------------
__global__ __launch_bounds__(256) void k_n2(const _Float16* __restrict__ feat_h,
                                            float* __restrict__ n2) {
  const int lane = threadIdx.x & 63;
  const int cb = lane & 7;
  const int g = lane >> 3;
  const int quad = blockIdx.x * 32 + (int)(threadIdx.x >> 6) * 8 + g;
  const int a = quad >> 8;
  const int b = quad & 255;
  const int ra[3] = {max(a - 1, 0), a, min(a + 1, 255)};
  const int cbn[3] = {max(b - 1, 0), b, min(b + 1, 255)};

  const h8* fp = (const h8*)feat_h;
  H8 F[3][3];
#pragma unroll
  for (int i = 0; i < 3; ++i)
#pragma unroll
    for (int j = 0; j < 3; ++j)
      F[i][j].v = fp[(size_t)((ra[i] << 8) + cbn[j]) * 8 + cb];

  h2 wyh[2], wxh[2];
  int cye[2], cxe[2];
#pragma unroll
  for (int e = 0; e < 2; ++e) {
    const float yf = fminf(fmaxf((float)(2 * a + e) * 0.5f - 0.25f, 0.0f), 255.0f);
    const int y0 = min((int)yf, 254);
    wyh[e].x = wyh[e].y = (_Float16)(yf - (float)y0);
    cye[e] = y0 - (a - 1);
    const float xf = fminf(fmaxf((float)(2 * b + e) * 0.5f - 0.25f, 0.0f), 255.0f);
    const int x0 = min((int)xf, 254);
    wxh[e].x = wxh[e].y = (_Float16)(xf - (float)x0);
    cxe[e] = x0 - (b - 1);
  }

  H8 colv[3][2];
#pragma unroll
  for (int r = 0; r < 3; ++r)
#pragma unroll
    for (int e = 0; e < 2; ++e) {
      const bool s1 = (cxe[e] == 1);
#pragma unroll
      for (int q = 0; q < 4; ++q) {
        const h2 A = s1 ? F[r][1].h[q] : F[r][0].h[q];
        const h2 B = s1 ? F[r][2].h[q] : F[r][1].h[q];
        colv[r][e].h[q] = A + wxh[e] * (B - A);
      }
    }

  float sq[4];
#pragma unroll
  for (int ey = 0; ey < 2; ++ey)
#pragma unroll
    for (int ex = 0; ex < 2; ++ex) {
      const bool s1 = (cye[ey] == 1);
      float nn = 0.0f;
#pragma unroll
      for (int q = 0; q < 4; ++q) {
        const h2 A = s1 ? colv[1][ex].h[q] : colv[0][ex].h[q];
        const h2 B = s1 ? colv[2][ex].h[q] : colv[1][ex].h[q];
        const h2 v = A + wyh[ey] * (B - A);
        nn = fdot2(v, v, nn);
      }
      sq[ey * 2 + ex] = nn;
    }

  const bool b0 = lane & 1, b1 = lane & 2;
  float m0 = merge2(sq[0], sq[1], b0, 1);
  float m1 = merge2(sq[2], sq[3], b0, 1);
  float mm = merge2(m0, m1, b1, 2);
  mm += __shfl_xor(mm, 4, 64);
  // lane (L&7)<4 holds site (ey,ex) = ((L>>1)&1, L&1) of its quad
  if ((lane & 7) < 4)
    n2[(2 * a + ((lane >> 1) & 1)) * 512 + 2 * b + (lane & 1)] = mm;
}

// ---------------------------------------------------------------------------
// Main kernel: TWO pixels per wave (px = lane>>5). Per px: 32 lanes =
// (site-group g2 = (L>>3)&3) x (channel-block cb = L&7), 4 loads/lane cover
// the 16-site patch. After the multiplexed reduce, lane L holds
// D'_{px, s} for s = (L&3)*4 + ((L>>3)&3); src lane for (P,s) is
// (P<<5) | ((s&3)<<3) | (s>>2).  D'_s = F_s.c - 0.5*||c||^2.
// Tap stage: t' = L&31 < 25 handles tap (t'/5, t'%5) of its px.
// Vote: two sequential 9-iter phases (one per px), den folded into the loop.
// ---------------------------------------------------------------------------
__global__ __launch_bounds__(256) void k_main(const float* __restrict__ grid_inte,
                                              const float* __restrict__ grid,
                                              const _Float16* __restrict__ feat_h,
                                              const _Float16* __restrict__ lbs_h,
                                              const float* __restrict__ n2,
                                              const float* __restrict__ wei_p,
                                              float* __restrict__ out) {
  const int lane = threadIdx.x & 63;
  const int P = lane >> 5;
  const int m0 = rfl((int)blockIdx.x * 8 + (int)(threadIdx.x >> 6) * 2);
  const int m = m0 + P;

  const float dx = grid[(2 * 512 + 2) * 2 + 0] - grid[(1 * 512 + 2) * 2 + 0];
  const float dy = grid[(2 * 512 + 2) * 2 + 1] - grid[(2 * 512 + 1) * 2 + 1];
  const float wei = wei_p[0];

  const float gi0 = grid_inte[m * 2 + 0];
  const float gi1 = grid_inte[m * 2 + 1];
  const int rp0 = (int)floorf(gi0 / dx);   // per-lane (per-px) now
  const int rp1 = (int)floorf(gi1 / dy);
  const int by = (rp0 - 3) >> 1;
  const int bx = (rp1 - 3) >> 1;

  const int cb = lane & 7;
  const int g2 = (lane >> 3) & 3;
  const h8* fp = (const h8*)feat_h;

  // ---- Issue feat loads: center + 4 patch rows (xx fixed per lane) ----
  H8 C, Pk[4];
  C.v = fp[(size_t)m * 8 + cb];
  const int xx = min(max(bx + g2, 0), 255);
#pragma unroll
  for (int k = 0; k < 4; ++k) {
    const int yy = min(max(by + k, 0), 255);
    Pk[k].v = fp[(size_t)((yy << 8) + xx) * 8 + cb];
  }

  // ---- Tap geometry (VALU only, overlaps loads) ----
  const int t = lane & 31;
  const int ti = (t * 13) >> 6;  // t/5 for t <= 31
  const int tj = t - 5 * ti;
  const int r5 = min(max(rp0 + ti - 2, 0), 511);
  const int c5 = min(max(rp1 + tj - 2, 0), 511);
  const float yf = fminf(fmaxf((float)r5 * 0.5f - 0.25f, 0.0f), 255.0f);
  const int y0 = min((int)yf, 254);
  const float wy = yf - (float)y0;
  const int qy = y0 - by;  // in [0,2] for t<25
  const float xf = fminf(fmaxf((float)c5 * 0.5f - 0.25f, 0.0f), 255.0f);
  const int x0 = min((int)xf, 254);
  const float wx = xf - (float)x0;
  const int qx = x0 - bx;
  const int lidx = r5 * 512 + c5;

  // ---- n2 gather (site-major: index is lidx) ----
  const float n2g = n2[lidx];

  // ---- Prefetch px0's 9 lbs vote gathers ----
  const int vg = (lane >= 42) ? 2 : ((lane >= 21) ? 1 : 0);
  const int cc = min(lane - 21 * vg, 20);
  float lg0[9];
#pragma unroll
  for (int it = 0; it < 9; ++it) {
    const int idxt = bpermi(3 * it + vg, lidx);  // px0 taps (clamped, in-bounds)
    lg0[it] = (float)lbs_h[idxt * 21 + cc];
  }

  // ---- Dot stage (consumes patch loads) ----
  float nhp = 0.0f;
#pragma unroll
  for (int q = 0; q < 4; ++q) nhp = fdot2(C.h[q], C.h[q], nhp);
  nhp *= -0.5f;
  float pr[4];
#pragma unroll
  for (int k = 0; k < 4; ++k) {
    float acc = nhp;
#pragma unroll
    for (int q = 0; q < 4; ++q) acc = fdot2(Pk[k].h[q], C.h[q], acc);
    pr[k] = acc;
  }
  // Multiplexed reduce: k-bits 0,1 <- lane bits 0,1; channel bit 2 via xor4.
  const bool hb0 = lane & 1, hb1 = lane & 2;
  float mm0 = merge2(pr[0], pr[1], hb0, 1);
  float mm1 = merge2(pr[2], pr[3], hb0, 1);
  float Dv = merge2(mm0, mm1, hb1, 2);
  Dv += __shfl_xor(Dv, 4, 64);
  // lane L holds D'_{P=L>>5, s=(L&3)*4+((L>>3)&3)}

  // ---- Bilinear in D' space (one bperm set serves both px) ----
  const int pb = P << 5;
  const int s00 = qy * 4 + qx;
  const int s01 = s00 + 1, s10 = s00 + 4, s11 = s00 + 5;
  const int l00 = pb | ((s00 & 3) << 3) | (s00 >> 2);
  const int l01 = pb | ((s01 & 3) << 3) | (s01 >> 2);
  const int l10 = pb | ((s10 & 3) << 3) | (s10 >> 2);
  const int l11 = pb | ((s11 & 3) << 3) | (s11 >> 2);
  const float d00 = bperm(l00, Dv);
  const float d01 = bperm(l01, Dv);
  const float d10 = bperm(l10, Dv);
  const float d11 = bperm(l11, Dv);
  const float lo = fmaf(wx, d01 - d00, d00);
  const float hi = fmaf(wx, d11 - d10, d10);
  const float crossD = fmaf(wy, hi - lo, lo);

  const float mse = fmaf(-2.0f, crossD, n2g) * 0.015625f;  // /64
  float dist = __expf(-wei * mse);
  dist = (t < 25) ? dist : 0.0f;   // lanes 25..31 of each px masked

  // ---- Issue px1's lbs gathers (hidden under px0's vote phase) ----
  float lg1[9];
#pragma unroll
  for (int it = 0; it < 9; ++it) {
    const int idxt = bpermi(32 + 3 * it + vg, lidx);
    lg1[it] = (float)lbs_h[idxt * 21 + cc];
  }

  // ---- Vote phase A (px0), den folded ----
  float voteA = 0.0f, dsumA = 0.0f;
#pragma unroll
  for (int it = 0; it < 9; ++it) {
    const float dt = bperm(3 * it + vg, dist);
    voteA = fmaf(lg0[it], dt, voteA);
    dsumA += dt;
  }
  const float vA = voteA + bperm(lane + 21, voteA) + bperm(lane + 42, voteA);
  const float dA = dsumA + bperm(lane + 21, dsumA) + bperm(lane + 42, dsumA);

  // ---- Vote phase B (px1) ----
  float voteB = 0.0f, dsumB = 0.0f;
#pragma unroll
  for (int it = 0; it < 9; ++it) {
    const float dt = bperm(32 + 3 * it + vg, dist);
    voteB = fmaf(lg1[it], dt, voteB);
    dsumB += dt;
  }
  const float vB = voteB + bperm(lane + 21, voteB) + bperm(lane + 42, voteB);
  const float dB = dsumB + bperm(lane + 21, dsumB) + bperm(lane + 42, dsumB);

  if (lane < 21) {
    out[lane * M_TOT + m0]     = vA / fmaxf(dA, 1e-15f);
    out[lane * M_TOT + m0 + 1] = vB / fmaxf(dB, 1e-15f);
  }
}

extern "C" void kernel_launch(void* const* d_in, const int* in_sizes, int n_in,
                              void* d_out, int out_size, void* d_ws, size_t ws_size,
                              hipStream_t stream) {
  const float* grid_inte = (const float*)d_in[0];  // (1,256,256,2)
  const float* grid      = (const float*)d_in[1];  // (1,512,512,2)
  const float* feat      = (const float*)d_in[2];  // (1,64,256,256)
  const float* lbs       = (const float*)d_in[3];  // (1,21,512,512)
  const float* wei       = (const float*)d_in[4];  // scalar
  float* out = (float*)d_out;                      // (1,21,256,256)

  char* ws = (char*)d_ws;
  _Float16* feat_h = (_Float16*)ws;                 // 8,388,608 B
  _Float16* lbs_h  = (_Float16*)(ws + 8388608);     // 11,010,048 B
  float*    n2v    = (float*)(ws + 19398656);       // 1,048,576 B (site-major)

  hipLaunchKernelGGL(k_prep, dim3(2048), dim3(256), 0, stream, feat, lbs, feat_h, lbs_h);
  hipLaunchKernelGGL(k_n2, dim3(M_TOT / 32), dim3(256), 0, stream, feat_h, n2v);
  hipLaunchKernelGGL(k_main, dim3(M_TOT / 8), dim3(256), 0, stream,
                     grid_inte, grid, feat_h, lbs_h, n2v, wei, out);
}

// Round 9
// 50.778 us; speedup vs baseline: 1.5854x; 1.1603x over previous
//
#include <hip/hip_runtime.h>
#include <stdint.h>

// Problem constants (N=1, D=64, NCLS=21, R=C=512, R_IN=C_IN=256)
#define M_TOT 65536   // R_IN*C_IN
#define LBS_S 262144  // R*C
#define REC   24      // per-site record: n2(fp16) + 21 x lbs(u8) + 1 pad

typedef _Float16 h2 __attribute__((ext_vector_type(2)));
typedef _Float16 h8 __attribute__((ext_vector_type(8)));
typedef float fx2 __attribute__((ext_vector_type(2)));
union H8 { h8 v; h2 h[4]; };

__device__ __forceinline__ int rfl(int v) { return __builtin_amdgcn_readfirstlane(v); }
__device__ __forceinline__ float bperm(int l, float v) {
  return __int_as_float(__builtin_amdgcn_ds_bpermute(l << 2, __float_as_int(v)));
}
__device__ __forceinline__ int bpermi(int l, int v) {
  return __builtin_amdgcn_ds_bpermute(l << 2, v);
}
// Multiplexed butterfly merge: lanes with `hi` keep reducing b, others a.
__device__ __forceinline__ float merge2(float a, float b, bool hi, int xo) {
  const float keep = hi ? b : a;
  const float send = hi ? a : b;
  return keep + __shfl_xor(send, xo, 64);
}

#if __has_builtin(__builtin_amdgcn_fdot2)
__device__ __forceinline__ float fdot2(h2 a, h2 b, float c) {
  return __builtin_amdgcn_fdot2(a, b, c, false);
}
#else
__device__ __forceinline__ float fdot2(h2 a, h2 b, float c) {
  return fmaf((float)a.x, (float)b.x, fmaf((float)a.y, (float)b.y, c));
}
#endif

// ---------------- fp8 e4m3fn pack/unpack (HW path + SW fallback) ----------
#if __has_builtin(__builtin_amdgcn_cvt_pk_f32_fp8) && __has_builtin(__builtin_amdgcn_cvt_pk_fp8_f32)
#define FP8_HW 1
#endif

__device__ __forceinline__ uint32_t enc1_sw(float x) {
  uint32_t b = __float_as_uint(x);
  const uint32_t s = b >> 31;
  uint32_t ax = b & 0x7fffffffu;
  if (ax > 0x43e00000u) ax = 0x43e00000u;  // clamp to 448
  const int e = (int)(ax >> 23) - 127;
  uint32_t out;
  if (e >= -6) {
    const uint32_t r = ax + 0x00080000u;  // round-half-up at 3-bit mantissa
    const int e2 = (int)(r >> 23) - 127;
    if (e2 > 8) out = (15u << 3) | 6u;    // 448
    else out = ((uint32_t)(e2 + 7) << 3) | ((r >> 20) & 7u);
  } else if (e >= -10) {
    const float af = __uint_as_float(ax);
    int m = (int)(af * 512.0f + 0.5f);    // subnormal step 2^-9
    out = (m > 7) ? ((1u << 3) | 0u) : (uint32_t)m;
  } else {
    out = 0;
  }
  return out | (s << 7);
}
__device__ __forceinline__ float dec1_sw(uint32_t b) {
  const uint32_t e = (b >> 3) & 15u, m = b & 7u;
  float f;
  if (e) f = __uint_as_float(((e + 120u) << 23) | (m << 20));
  else f = (float)m * 0.001953125f;  // m * 2^-9
  return (b & 0x80u) ? -f : f;
}

__device__ __forceinline__ uint32_t enc_pk4(float a, float b, float c, float d) {
#ifdef FP8_HW
  int r = __builtin_amdgcn_cvt_pk_fp8_f32(a, b, 0, false);
  r = __builtin_amdgcn_cvt_pk_fp8_f32(c, d, r, true);
  return (uint32_t)r;
#else
  return enc1_sw(a) | (enc1_sw(b) << 8) | (enc1_sw(c) << 16) | (enc1_sw(d) << 24);
#endif
}
__device__ __forceinline__ void dec_pk8(uint32_t lo, uint32_t hi, float* o) {
#ifdef FP8_HW
  const fx2 a = __builtin_amdgcn_cvt_pk_f32_fp8((int)lo, false);
  const fx2 b = __builtin_amdgcn_cvt_pk_f32_fp8((int)lo, true);
  const fx2 c = __builtin_amdgcn_cvt_pk_f32_fp8((int)hi, false);
  const fx2 d = __builtin_amdgcn_cvt_pk_f32_fp8((int)hi, true);
  o[0] = a.x; o[1] = a.y; o[2] = b.x; o[3] = b.y;
  o[4] = c.x; o[5] = c.y; o[6] = d.x; o[7] = d.y;
#else
  o[0] = dec1_sw(lo & 255); o[1] = dec1_sw((lo >> 8) & 255);
  o[2] = dec1_sw((lo >> 16) & 255); o[3] = dec1_sw(lo >> 24);
  o[4] = dec1_sw(hi & 255); o[5] = dec1_sw((hi >> 8) & 255);
  o[6] = dec1_sw((hi >> 16) & 255); o[7] = dec1_sw(hi >> 24);
#endif
}

// ---------------------------------------------------------------------------
// Fused prep: blocks 0-1023: feat (64,65536)f32 -> feat_h (65536,64)fp16 AND
// feat_q (65536,64)fp8. Blocks 1024-2047: lbs (21,262144)f32 -> u8 into the
// 24B/site record (bytes 2..22; n2 slot filled later by k_n2).
// ---------------------------------------------------------------------------
__global__ __launch_bounds__(256) void k_prep(const float* __restrict__ feat,
                                              const float* __restrict__ lbs,
                                              _Float16* __restrict__ feat_h,
                                              uint8_t* __restrict__ feat_q,
                                              uint8_t* __restrict__ rec) {
  __shared__ float ldsf[64 * 65];
  const int l = threadIdx.x & 63;
  const int w = threadIdx.x >> 6;
  if (blockIdx.x < 1024) {
    float(*tile)[65] = (float(*)[65])ldsf;
    const int s0 = blockIdx.x * 64;
#pragma unroll
    for (int k = 0; k < 16; ++k) {
      const int d = w * 16 + k;
      tile[d][l] = feat[(size_t)d * M_TOT + s0 + l];
    }
    __syncthreads();
    // fp16 table (for center reads)
    const int lh = l & 31, hs = l >> 5;
    h2* out2 = (h2*)feat_h;
#pragma unroll
    for (int k = 0; k < 8; ++k) {
      const int s = w * 16 + 2 * k + hs;
      h2 v;
      v.x = (_Float16)tile[2 * lh][s];
      v.y = (_Float16)tile[2 * lh + 1][s];
      out2[(size_t)(s0 + s) * 32 + lh] = v;  // 256B coalesced
    }
    // fp8 table (for patch gathers): lane = (site-sub l>>3, chan-block l&7)
    uint2* outq = (uint2*)feat_q;
#pragma unroll
    for (int it = 0; it < 2; ++it) {
      const int s = w * 16 + it * 8 + (l >> 3);
      const int cb = l & 7;
      const float* col = &tile[8 * cb][s];
      uint2 u;
      u.x = enc_pk4(col[0 * 65], col[1 * 65], col[2 * 65], col[3 * 65]);
      u.y = enc_pk4(col[4 * 65], col[5 * 65], col[6 * 65], col[7 * 65]);
      outq[(size_t)(s0 + s) * 8 + cb] = u;  // 512B coalesced
    }
  } else {
    uint8_t* buf = ((uint8_t*)ldsf) + w * (64 * REC);
    const int sb = (blockIdx.x - 1024) * 256 + w * 64;
#pragma unroll
    for (int c = 0; c < 21; ++c)
      buf[l * REC + 2 + c] = (uint8_t)(lbs[(size_t)c * LBS_S + sb + l] * 255.0f + 0.5f);
    __syncthreads();
    const uint32_t* src = (const uint32_t*)buf;
    uint32_t* dst = (uint32_t*)(rec + (size_t)sb * REC);  // 64*24=1536B, aligned
#pragma unroll
    for (int k = 0; k < 6; ++k) dst[k * 64 + l] = src[k * 64 + l];  // 384 dwords
  }
}

// ---------------------------------------------------------------------------
// N2[site] = ||feat_grid[:, site]||^2 from the FP8 table (consistency with the
// expansion in k_main), written as fp16 into rec[site].n2. 8 quads per wave.
// ---------------------------------------------------------------------------
__global__ __launch_bounds__(256) void k_n2(const uint8_t* __restrict__ feat_q,
                                            uint8_t* __restrict__ rec) {
  const int lane = threadIdx.x & 63;
  const int cb = lane & 7;
  const int g = lane >> 3;
  const int quad = blockIdx.x * 32 + (int)(threadIdx.x >> 6) * 8 + g;
  const int a = quad >> 8;
  const int b = quad & 255;
  const int ra[3] = {max(a - 1, 0), a, min(a + 1, 255)};
  const int cbn[3] = {max(b - 1, 0), b, min(b + 1, 255)};

  const uint2* fq = (const uint2*)feat_q;
  float F[3][3][8];
#pragma unroll
  for (int i = 0; i < 3; ++i)
#pragma unroll
    for (int j = 0; j < 3; ++j) {
      const uint2 u = fq[(size_t)((ra[i] << 8) + cbn[j]) * 8 + cb];
      dec_pk8(u.x, u.y, F[i][j]);
    }

  float wye[2], wxe[2];
  int cye[2], cxe[2];
#pragma unroll
  for (int e = 0; e < 2; ++e) {
    const float yf = fminf(fmaxf((float)(2 * a + e) * 0.5f - 0.25f, 0.0f), 255.0f);
    const int y0 = min((int)yf, 254);
    wye[e] = yf - (float)y0;
    cye[e] = y0 - (a - 1);
    const float xf = fminf(fmaxf((float)(2 * b + e) * 0.5f - 0.25f, 0.0f), 255.0f);
    const int x0 = min((int)xf, 254);
    wxe[e] = xf - (float)x0;
    cxe[e] = x0 - (b - 1);
  }

  float colv[3][2][8];
#pragma unroll
  for (int r = 0; r < 3; ++r)
#pragma unroll
    for (int e = 0; e < 2; ++e) {
      const bool s1 = (cxe[e] == 1);
#pragma unroll
      for (int j = 0; j < 8; ++j) {
        const float A = s1 ? F[r][1][j] : F[r][0][j];
        const float B = s1 ? F[r][2][j] : F[r][1][j];
        colv[r][e][j] = fmaf(wxe[e], B - A, A);
      }
    }

  float sq[4];
#pragma unroll
  for (int ey = 0; ey < 2; ++ey)
#pragma unroll
    for (int ex = 0; ex < 2; ++ex) {
      const bool s1 = (cye[ey] == 1);
      float nn = 0.0f;
#pragma unroll
      for (int j = 0; j < 8; ++j) {
        const float A = s1 ? colv[1][ex][j] : colv[0][ex][j];
        const float B = s1 ? colv[2][ex][j] : colv[1][ex][j];
        const float v = fmaf(wye[ey], B - A, A);
        nn = fmaf(v, v, nn);
      }
      sq[ey * 2 + ex] = nn;
    }

  const bool b0 = lane & 1, b1 = lane & 2;
  float m0 = merge2(sq[0], sq[1], b0, 1);
  float m1 = merge2(sq[2], sq[3], b0, 1);
  float mm = merge2(m0, m1, b1, 2);
  mm += __shfl_xor(mm, 4, 64);
  if ((lane & 7) < 4) {
    const int ey = (lane >> 1) & 1, ex = lane & 1;
    *(_Float16*)(rec + (size_t)((2 * a + ey) * 512 + 2 * b + ex) * REC) = (_Float16)mm;
  }
}

// ---------------------------------------------------------------------------
// Main kernel: TWO pixels per wave (px = lane>>5); structure as round 8 but
// patch loads from the fp8 table (8B/lane) and tap-side reads from the fused
// 24B record (n2 fp16 + lbs u8 share cache lines).
// ---------------------------------------------------------------------------
__global__ __launch_bounds__(256) void k_main(const float* __restrict__ grid_inte,
                                              const float* __restrict__ grid,
                                              const _Float16* __restrict__ feat_h,
                                              const uint8_t* __restrict__ feat_q,
                                              const uint8_t* __restrict__ rec,
                                              const float* __restrict__ wei_p,
                                              float* __restrict__ out) {
  const int lane = threadIdx.x & 63;
  const int P = lane >> 5;
  const int m0 = rfl((int)blockIdx.x * 8 + (int)(threadIdx.x >> 6) * 2);
  const int m = m0 + P;

  const float dx = grid[(2 * 512 + 2) * 2 + 0] - grid[(1 * 512 + 2) * 2 + 0];
  const float dy = grid[(2 * 512 + 2) * 2 + 1] - grid[(2 * 512 + 1) * 2 + 1];
  const float wei = wei_p[0];

  const float gi0 = grid_inte[m * 2 + 0];
  const float gi1 = grid_inte[m * 2 + 1];
  const int rp0 = (int)floorf(gi0 / dx);
  const int rp1 = (int)floorf(gi1 / dy);
  const int by = (rp0 - 3) >> 1;
  const int bx = (rp1 - 3) >> 1;

  const int cb = lane & 7;
  const int g2 = (lane >> 3) & 3;
  const h8* fp = (const h8*)feat_h;
  const uint2* fq = (const uint2*)feat_q;

  // ---- Issue loads: center (fp16) + 4 patch rows (fp8, xx fixed per lane) --
  H8 C;
  C.v = fp[(size_t)m * 8 + cb];
  uint2 pk[4];
  const int xx = min(max(bx + g2, 0), 255);
#pragma unroll
  for (int k = 0; k < 4; ++k) {
    const int yy = min(max(by + k, 0), 255);
    pk[k] = fq[(size_t)((yy << 8) + xx) * 8 + cb];
  }

  // ---- Tap geometry (VALU only, overlaps loads) ----
  const int t = lane & 31;
  const int ti = (t * 13) >> 6;  // t/5
  const int tj = t - 5 * ti;
  const int r5 = min(max(rp0 + ti - 2, 0), 511);
  const int c5 = min(max(rp1 + tj - 2, 0), 511);
  const float yf = fminf(fmaxf((float)r5 * 0.5f - 0.25f, 0.0f), 255.0f);
  const int y0 = min((int)yf, 254);
  const float wy = yf - (float)y0;
  const int qy = y0 - by;  // in [0,2] for t<25
  const float xf = fminf(fmaxf((float)c5 * 0.5f - 0.25f, 0.0f), 255.0f);
  const int x0 = min((int)xf, 254);
  const float wx = xf - (float)x0;
  const int qx = x0 - bx;
  const int lidx = r5 * 512 + c5;

  // ---- n2 gather (fp16 in the fused record) ----
  const float n2g = (float)*(const _Float16*)(rec + (size_t)lidx * REC);

  // ---- Prefetch px0's 9 lbs vote gathers (u8, same lines as n2) ----
  const int vg = (lane >= 42) ? 2 : ((lane >= 21) ? 1 : 0);
  const int cc = min(lane - 21 * vg, 20);
  float lg0[9];
#pragma unroll
  for (int it = 0; it < 9; ++it) {
    const int idxt = bpermi(3 * it + vg, lidx);
    lg0[it] = (float)rec[(size_t)idxt * REC + 2 + cc];
  }

  // ---- Dot stage: decode fp8 patch, f32 fma against fp16 center ----
  float cf[8];
#pragma unroll
  for (int q = 0; q < 4; ++q) {
    cf[2 * q] = (float)C.h[q].x;
    cf[2 * q + 1] = (float)C.h[q].y;
  }
  float nhp = 0.0f;
#pragma unroll
  for (int q = 0; q < 4; ++q) nhp = fdot2(C.h[q], C.h[q], nhp);
  nhp *= -0.5f;
  float pr[4];
#pragma unroll
  for (int k = 0; k < 4; ++k) {
    float pp[8];
    dec_pk8(pk[k].x, pk[k].y, pp);
    float acc = nhp;
#pragma unroll
    for (int j = 0; j < 8; ++j) acc = fmaf(pp[j], cf[j], acc);
    pr[k] = acc;
  }
  const bool hb0 = lane & 1, hb1 = lane & 2;
  float mm0 = merge2(pr[0], pr[1], hb0, 1);
  float mm1 = merge2(pr[2], pr[3], hb0, 1);
  float Dv = merge2(mm0, mm1, hb1, 2);
  Dv += __shfl_xor(Dv, 4, 64);
  // lane L holds D'_{P=L>>5, s=(L&3)*4+((L>>3)&3)}

  // ---- Bilinear in D' space ----
  const int pb = P << 5;
  const int s00 = qy * 4 + qx;
  const int s01 = s00 + 1, s10 = s00 + 4, s11 = s00 + 5;
  const int l00 = pb | ((s00 & 3) << 3) | (s00 >> 2);
  const int l01 = pb | ((s01 & 3) << 3) | (s01 >> 2);
  const int l10 = pb | ((s10 & 3) << 3) | (s10 >> 2);
  const int l11 = pb | ((s11 & 3) << 3) | (s11 >> 2);
  const float d00 = bperm(l00, Dv);
  const float d01 = bperm(l01, Dv);
  const float d10 = bperm(l10, Dv);
  const float d11 = bperm(l11, Dv);
  const float lo = fmaf(wx, d01 - d00, d00);
  const float hi = fmaf(wx, d11 - d10, d10);
  const float crossD = fmaf(wy, hi - lo, lo);

  const float mse = fmaf(-2.0f, crossD, n2g) * 0.015625f;  // /64
  float dist = __expf(-wei * mse);
  dist = (t < 25) ? dist : 0.0f;

  // ---- Issue px1's lbs gathers (hidden under px0's vote phase) ----
  float lg1[9];
#pragma unroll
  for (int it = 0; it < 9; ++it) {
    const int idxt = bpermi(32 + 3 * it + vg, lidx);
    lg1[it] = (float)rec[(size_t)idxt * REC + 2 + cc];
  }

  // ---- Vote phase A (px0), den folded ----
  float voteA = 0.0f, dsumA = 0.0f;
#pragma unroll
  for (int it = 0; it < 9; ++it) {
    const float dt = bperm(3 * it + vg, dist);
    voteA = fmaf(lg0[it], dt, voteA);
    dsumA += dt;
  }
  const float vA = voteA + bperm(lane + 21, voteA) + bperm(lane + 42, voteA);
  const float dA = dsumA + bperm(lane + 21, dsumA) + bperm(lane + 42, dsumA);

  // ---- Vote phase B (px1) ----
  float voteB = 0.0f, dsumB = 0.0f;
#pragma unroll
  for (int it = 0; it < 9; ++it) {
    const float dt = bperm(32 + 3 * it + vg, dist);
    voteB = fmaf(lg1[it], dt, voteB);
    dsumB += dt;
  }
  const float vB = voteB + bperm(lane + 21, voteB) + bperm(lane + 42, voteB);
  const float dB = dsumB + bperm(lane + 21, dsumB) + bperm(lane + 42, dsumB);

  const float s255 = 1.0f / 255.0f;  // u8 lbs dequant
  if (lane < 21) {
    out[lane * M_TOT + m0]     = vA * s255 / fmaxf(dA, 1e-15f);
    out[lane * M_TOT + m0 + 1] = vB * s255 / fmaxf(dB, 1e-15f);
  }
}

extern "C" void kernel_launch(void* const* d_in, const int* in_sizes, int n_in,
                              void* d_out, int out_size, void* d_ws, size_t ws_size,
                              hipStream_t stream) {
  const float* grid_inte = (const float*)d_in[0];  // (1,256,256,2)
  const float* grid      = (const float*)d_in[1];  // (1,512,512,2)
  const float* feat      = (const float*)d_in[2];  // (1,64,256,256)
  const float* lbs       = (const float*)d_in[3];  // (1,21,512,512)
  const float* wei       = (const float*)d_in[4];  // scalar
  float* out = (float*)d_out;                      // (1,21,256,256)

  char* ws = (char*)d_ws;
  _Float16* feat_h = (_Float16*)ws;                 // 8,388,608 B
  uint8_t*  feat_q = (uint8_t*)(ws + 8388608);      // 4,194,304 B
  uint8_t*  rec    = (uint8_t*)(ws + 12582912);     // 6,291,456 B (262144 x 24)

  hipLaunchKernelGGL(k_prep, dim3(2048), dim3(256), 0, stream, feat, lbs, feat_h, feat_q, rec);
  hipLaunchKernelGGL(k_n2, dim3(M_TOT / 32), dim3(256), 0, stream, feat_q, rec);
  hipLaunchKernelGGL(k_main, dim3(M_TOT / 8), dim3(256), 0, stream,
                     grid_inte, grid, feat_h, feat_q, rec, wei, out);
}